// Round 7
// baseline (867.462 us; speedup 1.0000x reference)
//
#include <hip/hip_runtime.h>
#include <hip/hip_cooperative_groups.h>

namespace cg = cooperative_groups;

#define N_NODES 50000
#define N_EDGES 640000
#define NSCANB  196   // ceil(50000/256) logical scan blocks

// workspace layout (4B units)
#define OFF_HTMPB    0          // ushort[6400000] bf16 h=xW
#define OFF_OBF      3200000    // ushort[6400000] bf16 copy of out
#define OFF_DEG      6400000    // int[50000]
#define OFF_ROWSTART 6450000    // int[50001]
#define OFF_CURSOR   6500016    // int[50000]
#define OFF_DINV     6550016    // float[50000]
#define OFF_E        6600016    // float[50000]
#define OFF_SCAL     6650016    // [0]=EminBits [1]=S0 [2]=S1
#define OFF_BLKSUM   6650020    // int[256]
#define OFF_ESRC     6650276    // int[640000]

typedef __attribute__((ext_vector_type(4))) short bf16x4;
typedef __attribute__((ext_vector_type(8))) short bf16x8;
typedef __attribute__((ext_vector_type(4))) float f32x4;

__device__ __forceinline__ unsigned short f2bf(float f) {  // RNE
    unsigned u = __float_as_uint(f);
    unsigned r = u + 0x7fffu + ((u >> 16) & 1u);
    return (unsigned short)(r >> 16);
}
__device__ __forceinline__ float bflo(unsigned u) { return __uint_as_float(u << 16); }
__device__ __forceinline__ float bfhi(unsigned u) { return __uint_as_float(u & 0xffff0000u); }

__global__ __launch_bounds__(256, 4) void k_fused(
    const float* __restrict__ x, const int* __restrict__ ei,
    const float* __restrict__ weight, const float* __restrict__ temp,
    const float* __restrict__ W, const float* __restrict__ bias,
    float* __restrict__ out, float* __restrict__ ws)
{
    cg::grid_group grid = cg::this_grid();
    const int* src = ei;
    const int* dst = ei + N_EDGES;
    unsigned short* htmpb = (unsigned short*)(ws + OFF_HTMPB);
    unsigned short* obf   = (unsigned short*)(ws + OFF_OBF);
    int*   deg      = (int*)(ws + OFF_DEG);
    int*   rowstart = (int*)(ws + OFF_ROWSTART);
    int*   cursor   = (int*)(ws + OFF_CURSOR);
    float* dinv     = ws + OFF_DINV;
    float* E        = ws + OFF_E;
    float* scal     = ws + OFF_SCAL;
    int*   blksum   = (int*)(ws + OFF_BLKSUM);
    int*   esrc     = (int*)(ws + OFF_ESRC);

    const int tid  = threadIdx.x;
    const int gtid = blockIdx.x * 256 + tid;
    const int gsz  = gridDim.x * 256;

    __shared__ union {
        unsigned short wt[128 * 132];   // bf16 W^T  (33792 B)
        int scan[256];
    } u;
    __shared__ int   ired[8];
    __shared__ float fred[8];

    // ---- P0: zero deg + scal ----
    for (int i = gtid; i < N_NODES; i += gsz) deg[i] = 0;
    if (gtid == 0) { ((int*)scal)[0] = 0x7F7FFFFF; scal[1] = 0.f; scal[2] = 0.f; }
    grid.sync();

    // ---- P1a: degree atomics ----
    for (int e = gtid; e < N_EDGES; e += gsz) atomicAdd(&deg[dst[e]], 1);

    // ---- P1b: GEMM htmpb = bf16(x @ W), MFMA 16x16x32 ----
    if (blockIdx.x < 782) {
        // stage W^T bf16 once per block
        for (int i = tid; i < 4096; i += 256) {
            int k = i >> 5, n4 = (i & 31) * 4;
            float4 v = *(const float4*)(W + k * 128 + n4);
            u.wt[(n4 + 0) * 132 + k] = f2bf(v.x);
            u.wt[(n4 + 1) * 132 + k] = f2bf(v.y);
            u.wt[(n4 + 2) * 132 + k] = f2bf(v.z);
            u.wt[(n4 + 3) * 132 + k] = f2bf(v.w);
        }
        __syncthreads();
        int wave = tid >> 6, lane = tid & 63, quad = lane >> 4, m16 = lane & 15;
        for (int t = blockIdx.x; t < 782; t += gridDim.x) {
            int r0 = t * 64;
            int arow = r0 + wave * 16 + m16;
            int rowc = arow < N_NODES ? arow : N_NODES - 1;
            f32x4 acc[8];
            #pragma unroll
            for (int c = 0; c < 8; c++) acc[c] = (f32x4){0.f, 0.f, 0.f, 0.f};
            #pragma unroll
            for (int kt = 0; kt < 4; kt++) {
                int koff = kt * 32 + quad * 8;
                float4 xa = *(const float4*)(x + rowc * 128 + koff);
                float4 xb = *(const float4*)(x + rowc * 128 + koff + 4);
                bf16x8 af;
                af[0] = (short)f2bf(xa.x); af[1] = (short)f2bf(xa.y);
                af[2] = (short)f2bf(xa.z); af[3] = (short)f2bf(xa.w);
                af[4] = (short)f2bf(xb.x); af[5] = (short)f2bf(xb.y);
                af[6] = (short)f2bf(xb.z); af[7] = (short)f2bf(xb.w);
                #pragma unroll
                for (int c = 0; c < 8; c++) {
                    bf16x4 bl = *(const bf16x4*)(u.wt + (c * 16 + m16) * 132 + koff);
                    bf16x4 bh = *(const bf16x4*)(u.wt + (c * 16 + m16) * 132 + koff + 4);
                    bf16x8 bfrag = __builtin_shufflevector(bl, bh, 0, 1, 2, 3, 4, 5, 6, 7);
                    acc[c] = __builtin_amdgcn_mfma_f32_16x16x32_bf16(af, bfrag, acc[c], 0, 0, 0);
                }
            }
            // C/D: col = lane&15, row = quad*4 + reg
            #pragma unroll
            for (int reg = 0; reg < 4; reg++) {
                int grow = r0 + wave * 16 + quad * 4 + reg;
                if (grow < N_NODES) {
                    #pragma unroll
                    for (int c = 0; c < 8; c++)
                        htmpb[grow * 128 + c * 16 + m16] = f2bf(acc[c][reg]);
                }
            }
        }
    }
    grid.sync();

    // ---- P2: scan step A (local exclusive prefix + block sums + dinv) ----
    for (int vb = blockIdx.x; vb < NSCANB; vb += gridDim.x) {
        int i = vb * 256 + tid;
        int v = (i < N_NODES) ? deg[i] : 0;
        if (i < N_NODES) dinv[i] = rsqrtf((float)(v + 1));  // +1 self-loop
        u.scan[tid] = v;
        __syncthreads();
        #pragma unroll
        for (int off = 1; off < 256; off <<= 1) {
            int t2 = (tid >= off) ? u.scan[tid - off] : 0;
            __syncthreads();
            u.scan[tid] += t2;
            __syncthreads();
        }
        if (i < N_NODES) rowstart[i] = u.scan[tid] - v;  // local exclusive
        if (tid == 255) blksum[vb] = u.scan[255];
        __syncthreads();
    }
    grid.sync();

    // ---- P3: add block offsets, zero cursors ----
    for (int vb = blockIdx.x; vb < NSCANB; vb += gridDim.x) {
        int lane = tid & 63, wid = tid >> 6;
        int p = (tid < vb) ? blksum[tid] : 0;  // vb <= 195 < 256
        #pragma unroll
        for (int off = 32; off; off >>= 1) p += __shfl_xor(p, off);
        if (lane == 0) ired[wid] = p;
        __syncthreads();
        int offp = ired[0] + ired[1] + ired[2] + ired[3];
        int i = vb * 256 + tid;
        if (i < N_NODES) { rowstart[i] += offp; cursor[i] = 0; }
        __syncthreads();
    }
    if (gtid == 0) rowstart[N_NODES] = N_EDGES;
    grid.sync();

    // ---- P4: bucket edges into CSR ----
    for (int e = gtid; e < N_EDGES; e += gsz) {
        int d = dst[e];
        int pos = atomicAdd(&cursor[d], 1);
        esrc[rowstart[d] + pos] = src[e];
    }
    grid.sync();

    // ---- P5: gather (GCN aggregate) -> out (f32) + obf (bf16) ----
    {
        int lane = tid & 31;
        for (int node = blockIdx.x * 8 + (tid >> 5); node < N_NODES; node += gridDim.x * 8) {
            float di = dinv[node];
            float4 bv = *(const float4*)(bias + lane * 4);
            uint2 hv = *(const uint2*)(htmpb + node * 128 + lane * 4);
            float sl = di * di;
            float ax = bv.x + bflo(hv.x) * sl, ay = bv.y + bfhi(hv.x) * sl;
            float az = bv.z + bflo(hv.y) * sl, aw = bv.w + bfhi(hv.y) * sl;
            float cx = 0.f, cy = 0.f, cz = 0.f, cw = 0.f;
            int e0 = rowstart[node], e1 = rowstart[node + 1];
            int k = e0;
            for (; k + 1 < e1; k += 2) {
                int s0 = esrc[k], s1 = esrc[k + 1];
                float n0 = di * dinv[s0], n1 = di * dinv[s1];
                uint2 u0 = *(const uint2*)(htmpb + s0 * 128 + lane * 4);
                uint2 u1 = *(const uint2*)(htmpb + s1 * 128 + lane * 4);
                ax += bflo(u0.x) * n0; ay += bfhi(u0.x) * n0;
                az += bflo(u0.y) * n0; aw += bfhi(u0.y) * n0;
                cx += bflo(u1.x) * n1; cy += bfhi(u1.x) * n1;
                cz += bflo(u1.y) * n1; cw += bfhi(u1.y) * n1;
            }
            if (k < e1) {
                int s0 = esrc[k];
                float n0 = di * dinv[s0];
                uint2 u0 = *(const uint2*)(htmpb + s0 * 128 + lane * 4);
                ax += bflo(u0.x) * n0; ay += bfhi(u0.x) * n0;
                az += bflo(u0.y) * n0; aw += bfhi(u0.y) * n0;
            }
            ax += cx; ay += cy; az += cz; aw += cw;
            *(float4*)(out + node * 128 + lane * 4) = make_float4(ax, ay, az, aw);
            uint2 pk;
            pk.x = (unsigned)f2bf(ax) | ((unsigned)f2bf(ay) << 16);
            pk.y = (unsigned)f2bf(az) | ((unsigned)f2bf(aw) << 16);
            *(uint2*)(obf + node * 128 + lane * 4) = pk;
        }
    }
    grid.sync();

    // ---- P6: energy E[d] = sum ||out_s - out_d||^2 (bf16 gather) ----
    {
        int lane = tid & 31;
        for (int node = blockIdx.x * 8 + (tid >> 5); node < N_NODES; node += gridDim.x * 8) {
            uint2 ud = *(const uint2*)(obf + node * 128 + lane * 4);
            float o0 = bflo(ud.x), o1 = bfhi(ud.x), o2 = bflo(ud.y), o3 = bfhi(ud.y);
            float acc = 0.f, acc2 = 0.f;
            int e0 = rowstart[node], e1 = rowstart[node + 1];
            int k = e0;
            for (; k + 1 < e1; k += 2) {
                int s0 = esrc[k], s1 = esrc[k + 1];
                uint2 a = *(const uint2*)(obf + s0 * 128 + lane * 4);
                uint2 c = *(const uint2*)(obf + s1 * 128 + lane * 4);
                float d0 = bflo(a.x) - o0, d1 = bfhi(a.x) - o1;
                float d2 = bflo(a.y) - o2, d3 = bfhi(a.y) - o3;
                float e4 = bflo(c.x) - o0, e5 = bfhi(c.x) - o1;
                float e6 = bflo(c.y) - o2, e7 = bfhi(c.y) - o3;
                acc  += d0 * d0 + d1 * d1 + d2 * d2 + d3 * d3;
                acc2 += e4 * e4 + e5 * e5 + e6 * e6 + e7 * e7;
            }
            if (k < e1) {
                int s0 = esrc[k];
                uint2 a = *(const uint2*)(obf + s0 * 128 + lane * 4);
                float d0 = bflo(a.x) - o0, d1 = bfhi(a.x) - o1;
                float d2 = bflo(a.y) - o2, d3 = bfhi(a.y) - o3;
                acc += d0 * d0 + d1 * d1 + d2 * d2 + d3 * d3;
            }
            acc += acc2;
            #pragma unroll
            for (int off = 16; off; off >>= 1) acc += __shfl_xor(acc, off);
            if (lane == 0) E[node] = acc;
        }
    }
    grid.sync();

    // ---- P7: Emin ----
    {
        float v = 3.402823466e38f;
        for (int i = gtid; i < N_NODES; i += gsz) v = fminf(v, E[i]);
        int lane = tid & 63, wid = tid >> 6;
        #pragma unroll
        for (int off = 32; off; off >>= 1) v = fminf(v, __shfl_xor(v, off));
        if (lane == 0) fred[wid] = v;
        __syncthreads();
        if (tid == 0) {
            float m = fminf(fminf(fred[0], fred[1]), fminf(fred[2], fred[3]));
            atomicMin((int*)scal, __float_as_int(m));  // valid: E >= 0
        }
    }
    grid.sync();

    // ---- P8: S0 = sum e^dd, S1 = sum e^dd*dd ----
    {
        float Emin = __int_as_float(((int*)scal)[0]);
        float T = temp[0];
        float s0 = 0.f, s1 = 0.f;
        for (int i = gtid; i < N_NODES; i += gsz) {
            float dd = (Emin - E[i]) / T;
            float ed = __expf(dd);
            s0 += ed; s1 += ed * dd;
        }
        int lane = tid & 63, wid = tid >> 6;
        #pragma unroll
        for (int off = 32; off; off >>= 1) { s0 += __shfl_xor(s0, off); s1 += __shfl_xor(s1, off); }
        if (lane == 0) { fred[wid] = s0; fred[wid + 4] = s1; }
        __syncthreads();
        if (tid == 0) {
            atomicAdd(&scal[1], fred[0] + fred[1] + fred[2] + fred[3]);
            atomicAdd(&scal[2], fred[4] + fred[5] + fred[6] + fred[7]);
        }
    }
    grid.sync();

    // ---- P9: entropy gradient, CSR-driven, skip q==0 nodes ----
    {
        float Emin = __int_as_float(((int*)scal)[0]);
        float S0 = scal[1], S1 = scal[2];
        float T = temp[0];
        float wscale = 2.f * weight[0];
        int lane = tid & 31;
        for (int node = blockIdx.x * 8 + (tid >> 5); node < N_NODES; node += gridDim.x * 8) {
            float dd = (Emin - E[node]) / T;
            float qd = (__expf(dd) / S0) * (dd - S1 / S0) / T;
            if (qd != 0.f) {
                float cc = wscale * qd;
                float4 od = *(const float4*)(out + node * 128 + lane * 4);
                float sx = 0.f, sy = 0.f, sz = 0.f, sw = 0.f;
                int e0 = rowstart[node], e1 = rowstart[node + 1];
                for (int k = e0; k < e1; k++) {
                    int s = esrc[k];
                    float4 a = *(const float4*)(out + s * 128 + lane * 4);
                    float vx = cc * (a.x - od.x), vy = cc * (a.y - od.y);
                    float vz = cc * (a.z - od.z), vw = cc * (a.w - od.w);
                    float* os = out + s * 128 + lane * 4;
                    atomicAdd(os + 0, vx); atomicAdd(os + 1, vy);
                    atomicAdd(os + 2, vz); atomicAdd(os + 3, vw);
                    sx += vx; sy += vy; sz += vz; sw += vw;
                }
                float* odp = out + node * 128 + lane * 4;
                atomicAdd(odp + 0, -sx); atomicAdd(odp + 1, -sy);
                atomicAdd(odp + 2, -sz); atomicAdd(odp + 3, -sw);
            }
        }
    }
}

extern "C" void kernel_launch(void* const* d_in, const int* in_sizes, int n_in,
                              void* d_out, int out_size, void* d_ws, size_t ws_size,
                              hipStream_t stream) {
    const float* x      = (const float*)d_in[0];
    const int*   ei     = (const int*)d_in[1];
    const float* weight = (const float*)d_in[2];
    const float* temp   = (const float*)d_in[3];
    const float* W      = (const float*)d_in[4];
    const float* bias   = (const float*)d_in[5];
    float* out = (float*)d_out;
    float* ws  = (float*)d_ws;

    int maxB = 0;
    if (hipOccupancyMaxActiveBlocksPerMultiprocessor(&maxB, k_fused, 256, 0) != hipSuccess || maxB <= 0)
        maxB = 2;  // conservative fallback
    int grid = maxB * 256;          // 256 CUs on MI355X
    if (grid > 2048) grid = 2048;

    void* args[8];
    args[0] = (void*)&x;     args[1] = (void*)&ei;
    args[2] = (void*)&weight; args[3] = (void*)&temp;
    args[4] = (void*)&W;     args[5] = (void*)&bias;
    args[6] = (void*)&out;   args[7] = (void*)&ws;
    hipLaunchCooperativeKernel((const void*)k_fused, dim3(grid), dim3(256), args, 0, stream);
}

// Round 8
// 308.798 us; speedup vs baseline: 2.8092x; 2.8092x over previous
//
#include <hip/hip_runtime.h>

#define N_NODES 50000
#define N_EDGES 640000
#define NSCANB  196   // ceil(50000/256)

// workspace layout (4B units)
#define OFF_HTMPB    0          // ushort[6400000] bf16 h=xW
#define OFF_OBF      3200000    // ushort[6400000] bf16 copy of out
#define OFF_DEG      6400000    // int[50000]
#define OFF_ROWSTART 6450000    // int[50001]
#define OFF_CURSOR   6500016    // int[50000]
#define OFF_DINV     6550016    // float[50000]
#define OFF_E        6600016    // float[50000]
#define OFF_SCAL     6650016    // [0]=EminBits [1]=S0 [2]=S1
#define OFF_BLKSUM   6650020    // int[256]
#define OFF_ESRC     6650276    // int[640000]

typedef __attribute__((ext_vector_type(4))) short bf16x4;
typedef __attribute__((ext_vector_type(8))) short bf16x8;
typedef __attribute__((ext_vector_type(4))) float f32x4;

__device__ __forceinline__ unsigned short f2bf(float f) {  // RNE
    unsigned u = __float_as_uint(f);
    unsigned r = u + 0x7fffu + ((u >> 16) & 1u);
    return (unsigned short)(r >> 16);
}
__device__ __forceinline__ float bflo(unsigned u) { return __uint_as_float(u << 16); }
__device__ __forceinline__ float bfhi(unsigned u) { return __uint_as_float(u & 0xffff0000u); }

__global__ __launch_bounds__(256) void k_init(float* ws) {
    int i = blockIdx.x * 256 + threadIdx.x;
    if (i < N_NODES) ((int*)(ws + OFF_DEG))[i] = 0;
    if (i == 0) {
        ((int*)(ws + OFF_SCAL))[0] = 0x7F7FFFFF;  // FLT_MAX bits
        ws[OFF_SCAL + 1] = 0.f;
        ws[OFF_SCAL + 2] = 0.f;
    }
}

// Fused: degree atomics (grid-stride prologue) + bf16 MFMA GEMM (one 64-row tile/block).
// grid = 782 = ceil(50000/64).
__global__ __launch_bounds__(256) void k_deg_gemm(const float* __restrict__ x,
                                                  const int* __restrict__ dst,
                                                  const float* __restrict__ W,
                                                  int* __restrict__ deg,
                                                  unsigned short* __restrict__ htmpb) {
    // ---- A: degree ----
    int gtid = blockIdx.x * 256 + threadIdx.x;
    for (int e = gtid; e < N_EDGES; e += 782 * 256) atomicAdd(&deg[dst[e]], 1);

    // ---- B: GEMM htmpb = bf16(x @ W) ----
    __shared__ unsigned short wt[128 * 132];   // bf16 W^T
    int tid = threadIdx.x;
    for (int i = tid; i < 4096; i += 256) {
        int k = i >> 5, n4 = (i & 31) * 4;
        float4 v = *(const float4*)(W + k * 128 + n4);
        wt[(n4 + 0) * 132 + k] = f2bf(v.x);
        wt[(n4 + 1) * 132 + k] = f2bf(v.y);
        wt[(n4 + 2) * 132 + k] = f2bf(v.z);
        wt[(n4 + 3) * 132 + k] = f2bf(v.w);
    }
    __syncthreads();

    int wave = tid >> 6, lane = tid & 63, quad = lane >> 4, m16 = lane & 15;
    int r0 = blockIdx.x * 64;
    int arow = r0 + wave * 16 + m16;
    int rowc = arow < N_NODES ? arow : N_NODES - 1;
    f32x4 acc[8];
    #pragma unroll
    for (int c = 0; c < 8; c++) acc[c] = (f32x4){0.f, 0.f, 0.f, 0.f};
    #pragma unroll
    for (int kt = 0; kt < 4; kt++) {
        int koff = kt * 32 + quad * 8;
        float4 xa = *(const float4*)(x + rowc * 128 + koff);
        float4 xb = *(const float4*)(x + rowc * 128 + koff + 4);
        bf16x8 af;
        af[0] = (short)f2bf(xa.x); af[1] = (short)f2bf(xa.y);
        af[2] = (short)f2bf(xa.z); af[3] = (short)f2bf(xa.w);
        af[4] = (short)f2bf(xb.x); af[5] = (short)f2bf(xb.y);
        af[6] = (short)f2bf(xb.z); af[7] = (short)f2bf(xb.w);
        #pragma unroll
        for (int c = 0; c < 8; c++) {
            bf16x4 bl = *(const bf16x4*)(wt + (c * 16 + m16) * 132 + koff);
            bf16x4 bh = *(const bf16x4*)(wt + (c * 16 + m16) * 132 + koff + 4);
            bf16x8 bfrag = __builtin_shufflevector(bl, bh, 0, 1, 2, 3, 4, 5, 6, 7);
            acc[c] = __builtin_amdgcn_mfma_f32_16x16x32_bf16(af, bfrag, acc[c], 0, 0, 0);
        }
    }
    // C/D: col = lane&15, row = quad*4 + reg
    #pragma unroll
    for (int reg = 0; reg < 4; reg++) {
        int grow = r0 + wave * 16 + quad * 4 + reg;
        if (grow < N_NODES) {
            #pragma unroll
            for (int c = 0; c < 8; c++)
                htmpb[grow * 128 + c * 16 + m16] = f2bf(acc[c][reg]);
        }
    }
}

// ---- scan step 1: local exclusive prefix + block sums + dinv ----
__global__ __launch_bounds__(256) void k_scan1(const int* __restrict__ deg,
                                               int* __restrict__ rowstart,
                                               int* __restrict__ blksum,
                                               float* __restrict__ dinv) {
    __shared__ int sh[256];
    int i = blockIdx.x * 256 + threadIdx.x;
    int v = (i < N_NODES) ? deg[i] : 0;
    if (i < N_NODES) dinv[i] = rsqrtf((float)(v + 1));  // +1 self-loop
    sh[threadIdx.x] = v;
    __syncthreads();
    #pragma unroll
    for (int off = 1; off < 256; off <<= 1) {
        int t = (threadIdx.x >= off) ? sh[threadIdx.x - off] : 0;
        __syncthreads();
        sh[threadIdx.x] += t;
        __syncthreads();
    }
    if (i < N_NODES) rowstart[i] = sh[threadIdx.x] - v;  // local exclusive
    if (threadIdx.x == 255) blksum[blockIdx.x] = sh[255];
}

// ---- scan steps 2+3 fused: each block re-reduces blksum[0..vb) for its offset ----
__global__ __launch_bounds__(256) void k_scan23(int* __restrict__ rowstart,
                                                const int* __restrict__ blksum,
                                                int* __restrict__ cursor) {
    __shared__ int ired[4];
    int vb = blockIdx.x, tid = threadIdx.x;
    int lane = tid & 63, wid = tid >> 6;
    int p = (tid < vb) ? blksum[tid] : 0;   // vb <= 195 < 256
    #pragma unroll
    for (int off = 32; off; off >>= 1) p += __shfl_xor(p, off);
    if (lane == 0) ired[wid] = p;
    __syncthreads();
    int offp = ired[0] + ired[1] + ired[2] + ired[3];
    int i = vb * 256 + tid;
    if (i < N_NODES) { rowstart[i] += offp; cursor[i] = 0; }
    if (vb == 0 && tid == 0) rowstart[N_NODES] = N_EDGES;
}

__global__ __launch_bounds__(256) void k_bucket(const int* __restrict__ src,
                                                const int* __restrict__ dst,
                                                const int* __restrict__ rowstart,
                                                int* __restrict__ cursor,
                                                int* __restrict__ esrc) {
    int e = blockIdx.x * 256 + threadIdx.x;
    int d = dst[e];
    int pos = atomicAdd(&cursor[d], 1);
    esrc[rowstart[d] + pos] = src[e];
}

// per node (32 lanes, 4 bf16 per lane via uint2), 2 chains:
// out[d] = b + htmp[d]*dinv[d]^2 + sum_s htmp[s]*dinv[s]*dinv[d]; also bf16 copy obf.
__global__ __launch_bounds__(256) void k_gather(const unsigned short* __restrict__ htmpb,
                                                const float* __restrict__ dinv,
                                                const float* __restrict__ b,
                                                const int* __restrict__ rowstart,
                                                const int* __restrict__ esrc,
                                                float* __restrict__ out,
                                                unsigned short* __restrict__ obf) {
    int node = blockIdx.x * 8 + (threadIdx.x >> 5);
    int lane = threadIdx.x & 31;
    float di = dinv[node];
    float4 bv = *(const float4*)(b + lane * 4);
    uint2 hv = *(const uint2*)(htmpb + node * 128 + lane * 4);
    float sl = di * di;
    float ax = bv.x + bflo(hv.x) * sl, ay = bv.y + bfhi(hv.x) * sl;
    float az = bv.z + bflo(hv.y) * sl, aw = bv.w + bfhi(hv.y) * sl;
    float cx = 0.f, cy = 0.f, cz = 0.f, cw = 0.f;
    int e0 = rowstart[node], e1 = rowstart[node + 1];
    int k = e0;
    for (; k + 1 < e1; k += 2) {
        int s0 = esrc[k], s1 = esrc[k + 1];
        float n0 = di * dinv[s0], n1 = di * dinv[s1];
        uint2 u0 = *(const uint2*)(htmpb + s0 * 128 + lane * 4);
        uint2 u1 = *(const uint2*)(htmpb + s1 * 128 + lane * 4);
        ax += bflo(u0.x) * n0; ay += bfhi(u0.x) * n0;
        az += bflo(u0.y) * n0; aw += bfhi(u0.y) * n0;
        cx += bflo(u1.x) * n1; cy += bfhi(u1.x) * n1;
        cz += bflo(u1.y) * n1; cw += bfhi(u1.y) * n1;
    }
    if (k < e1) {
        int s0 = esrc[k];
        float n0 = di * dinv[s0];
        uint2 u0 = *(const uint2*)(htmpb + s0 * 128 + lane * 4);
        ax += bflo(u0.x) * n0; ay += bfhi(u0.x) * n0;
        az += bflo(u0.y) * n0; aw += bfhi(u0.y) * n0;
    }
    ax += cx; ay += cy; az += cz; aw += cw;
    *(float4*)(out + node * 128 + lane * 4) = make_float4(ax, ay, az, aw);
    uint2 pk;
    pk.x = (unsigned)f2bf(ax) | ((unsigned)f2bf(ay) << 16);
    pk.y = (unsigned)f2bf(az) | ((unsigned)f2bf(aw) << 16);
    *(uint2*)(obf + node * 128 + lane * 4) = pk;
}

// per node: E[d] = sum ||out_s - out_d||^2 (bf16 gather, 2 chains) + fused block-min
__global__ __launch_bounds__(256) void k_energy(const unsigned short* __restrict__ obf,
                                                const int* __restrict__ rowstart,
                                                const int* __restrict__ esrc,
                                                float* __restrict__ E,
                                                int* __restrict__ scal) {
    __shared__ float smin[8];
    int node = blockIdx.x * 8 + (threadIdx.x >> 5);
    int lane = threadIdx.x & 31;
    uint2 ud = *(const uint2*)(obf + node * 128 + lane * 4);
    float o0 = bflo(ud.x), o1 = bfhi(ud.x), o2 = bflo(ud.y), o3 = bfhi(ud.y);
    float acc = 0.f, acc2 = 0.f;
    int e0 = rowstart[node], e1 = rowstart[node + 1];
    int k = e0;
    for (; k + 1 < e1; k += 2) {
        int s0 = esrc[k], s1 = esrc[k + 1];
        uint2 a = *(const uint2*)(obf + s0 * 128 + lane * 4);
        uint2 c = *(const uint2*)(obf + s1 * 128 + lane * 4);
        float d0 = bflo(a.x) - o0, d1 = bfhi(a.x) - o1;
        float d2 = bflo(a.y) - o2, d3 = bfhi(a.y) - o3;
        float e4 = bflo(c.x) - o0, e5 = bfhi(c.x) - o1;
        float e6 = bflo(c.y) - o2, e7 = bfhi(c.y) - o3;
        acc  += d0 * d0 + d1 * d1 + d2 * d2 + d3 * d3;
        acc2 += e4 * e4 + e5 * e5 + e6 * e6 + e7 * e7;
    }
    if (k < e1) {
        int s0 = esrc[k];
        uint2 a = *(const uint2*)(obf + s0 * 128 + lane * 4);
        float d0 = bflo(a.x) - o0, d1 = bfhi(a.x) - o1;
        float d2 = bflo(a.y) - o2, d3 = bfhi(a.y) - o3;
        acc += d0 * d0 + d1 * d1 + d2 * d2 + d3 * d3;
    }
    acc += acc2;
    #pragma unroll
    for (int off = 16; off; off >>= 1) acc += __shfl_xor(acc, off);
    if (lane == 0) { E[node] = acc; smin[threadIdx.x >> 5] = acc; }
    __syncthreads();
    if (threadIdx.x == 0) {
        float m = smin[0];
        #pragma unroll
        for (int g = 1; g < 8; g++) m = fminf(m, smin[g]);
        atomicMin(scal, __float_as_int(m));  // valid: E >= 0
    }
}

__global__ __launch_bounds__(256) void k_sums(const float* __restrict__ E,
                                              const float* __restrict__ temp,
                                              const int* __restrict__ scal,
                                              float* __restrict__ S) {
    __shared__ float sh0[4], sh1[4];
    float Emin = __int_as_float(scal[0]);
    float T = temp[0];
    int i = blockIdx.x * 256 + threadIdx.x;
    float s0 = 0.f, s1 = 0.f;
    if (i < N_NODES) {
        float dd = (Emin - E[i]) / T;
        float ed = __expf(dd);
        s0 = ed; s1 = ed * dd;
    }
    #pragma unroll
    for (int off = 32; off; off >>= 1) { s0 += __shfl_xor(s0, off); s1 += __shfl_xor(s1, off); }
    int lane = threadIdx.x & 63, wid = threadIdx.x >> 6;
    if (lane == 0) { sh0[wid] = s0; sh1[wid] = s1; }
    __syncthreads();
    if (threadIdx.x == 0) {
        atomicAdd(&S[0], sh0[0] + sh0[1] + sh0[2] + sh0[3]);
        atomicAdd(&S[1], sh1[0] + sh1[1] + sh1[2] + sh1[3]);
    }
}

// CSR-driven gradient with inline q (f32 out path): skip q==0 nodes (almost all).
__global__ __launch_bounds__(256) void k_grad(const int* __restrict__ rowstart,
                                              const int* __restrict__ esrc,
                                              const float* __restrict__ E,
                                              const float* __restrict__ temp,
                                              const float* __restrict__ scal,
                                              const float* __restrict__ weight,
                                              float* __restrict__ out) {
    int node = blockIdx.x * 8 + (threadIdx.x >> 5);
    int lane = threadIdx.x & 31;
    float Emin = __int_as_float(((const int*)scal)[0]);
    float S0 = scal[1], S1 = scal[2];
    float T = temp[0];
    float dd = (Emin - E[node]) / T;
    float qd = (__expf(dd) / S0) * (dd - S1 / S0) / T;
    if (qd == 0.f) return;
    float cc = 2.f * weight[0] * qd;
    float4 od = *(const float4*)(out + node * 128 + lane * 4);
    float sx = 0.f, sy = 0.f, sz = 0.f, sw = 0.f;
    int e0 = rowstart[node], e1 = rowstart[node + 1];
    for (int k = e0; k < e1; k++) {
        int s = esrc[k];
        float4 a = *(const float4*)(out + s * 128 + lane * 4);
        float vx = cc * (a.x - od.x), vy = cc * (a.y - od.y);
        float vz = cc * (a.z - od.z), vw = cc * (a.w - od.w);
        float* os = out + s * 128 + lane * 4;
        atomicAdd(os + 0, vx); atomicAdd(os + 1, vy);
        atomicAdd(os + 2, vz); atomicAdd(os + 3, vw);
        sx += vx; sy += vy; sz += vz; sw += vw;
    }
    float* odp = out + node * 128 + lane * 4;
    atomicAdd(odp + 0, -sx); atomicAdd(odp + 1, -sy);
    atomicAdd(odp + 2, -sz); atomicAdd(odp + 3, -sw);
}

extern "C" void kernel_launch(void* const* d_in, const int* in_sizes, int n_in,
                              void* d_out, int out_size, void* d_ws, size_t ws_size,
                              hipStream_t stream) {
    const float* x      = (const float*)d_in[0];
    const int*   ei     = (const int*)d_in[1];
    const float* weight = (const float*)d_in[2];
    const float* temp   = (const float*)d_in[3];
    const float* W      = (const float*)d_in[4];
    const float* b      = (const float*)d_in[5];
    float* out = (float*)d_out;
    float* ws  = (float*)d_ws;

    const int* src = ei;
    const int* dst = ei + N_EDGES;

    unsigned short* htmpb = (unsigned short*)(ws + OFF_HTMPB);
    unsigned short* obf   = (unsigned short*)(ws + OFF_OBF);
    int*   deg      = (int*)(ws + OFF_DEG);
    int*   rowstart = (int*)(ws + OFF_ROWSTART);
    int*   cursor   = (int*)(ws + OFF_CURSOR);
    float* dinv     = ws + OFF_DINV;
    float* Earr     = ws + OFF_E;
    float* scal     = ws + OFF_SCAL;
    int*   blksum   = (int*)(ws + OFF_BLKSUM);
    int*   esrc     = (int*)(ws + OFF_ESRC);

    k_init<<<NSCANB, 256, 0, stream>>>(ws);
    k_deg_gemm<<<782, 256, 0, stream>>>(x, dst, W, deg, htmpb);
    k_scan1<<<NSCANB, 256, 0, stream>>>(deg, rowstart, blksum, dinv);
    k_scan23<<<NSCANB, 256, 0, stream>>>(rowstart, blksum, cursor);
    k_bucket<<<N_EDGES / 256, 256, 0, stream>>>(src, dst, rowstart, cursor, esrc);
    k_gather<<<6250, 256, 0, stream>>>(htmpb, dinv, b, rowstart, esrc, out, obf);
    k_energy<<<6250, 256, 0, stream>>>(obf, rowstart, esrc, Earr, (int*)scal);
    k_sums<<<NSCANB, 256, 0, stream>>>(Earr, temp, (const int*)scal, scal + 1);
    k_grad<<<6250, 256, 0, stream>>>(rowstart, esrc, Earr, temp, scal, weight, out);
}